// Round 7
// baseline (742.828 us; speedup 1.0000x reference)
//
#include <hip/hip_runtime.h>

#define N_NODESC 100000
#define N_EDGESC 1600000
#define DIM 128
#define GB 782        // ceil(100000 / 128) gemm_in blocks
#define TPAD 136      // LDS tile row stride in shorts

// ---- fused gemm+bn geometry: 447 blocks x 448 threads (7 waves), 224-row tiles.
// Co-residency guaranteed: launch_bounds(448,4) caps VGPR<=128 (2 blocks/CU wave-wise),
// LDS 66.5KB -> 2 blocks/CU (133KB<=160KB); capacity 512 >= 447 -> barrier safe.
#define FB 447
#define FROWS 224

// ---- counting-sort CSR build geometry
#define NBUCK 391     // ceil(100000 / 256) coarse buckets (256 nodes each)
#define CSBLK 256     // chunk blocks
#define CHUNK 6250    // edges per chunk block (256 * 6250 = 1.6M exactly)
#define CAPB  6144    // LDS staging capacity per bucket (expect max ~4400)

typedef __bf16 bf16x8 __attribute__((ext_vector_type(8)));
typedef unsigned short u16x8 __attribute__((ext_vector_type(8)));
typedef float f32x4 __attribute__((ext_vector_type(4)));

__device__ __forceinline__ float asf(unsigned u) { return __uint_as_float(u); }
__device__ __forceinline__ unsigned short f2bf(float f) {
    unsigned u = __float_as_uint(f);
    u += 0x7fffu + ((u >> 16) & 1u);
    return (unsigned short)(u >> 16);
}
__device__ __forceinline__ bf16x8 pack8(const float* f) {
    u16x8 u;
    #pragma unroll
    for (int i = 0; i < 8; ++i) u[i] = f2bf(f[i]);
    return __builtin_bit_cast(bf16x8, u);
}

// ---------------- weight convert: 7 matrices fp32 [k][c] -> bf16 FRAGMENT-MAJOR:
// linear index = ((kt*8 + nt)*64 + lane)*8 + j  maps to  W[(kt*32 + quad*8 + j)*128 + nt*16 + l15]
__global__ __launch_bounds__(256) void k_wcvt(const float* __restrict__ w0, const float* __restrict__ w1,
                                              const float* __restrict__ w2, const float* __restrict__ w3,
                                              const float* __restrict__ w4, const float* __restrict__ w5,
                                              const float* __restrict__ w6, unsigned short* __restrict__ wt) {
    int gid = blockIdx.x * 256 + threadIdx.x;   // 0..114687
    int m = gid >> 14;
    int r = gid & 16383;
    int j = r & 7;
    int lane = (r >> 3) & 63;
    int nt = (r >> 9) & 7;
    int kt = (r >> 12) & 3;
    int quad = lane >> 4;
    int l15 = lane & 15;
    const float* src;
    switch (m) {
        case 0: src = w0; break; case 1: src = w1; break; case 2: src = w2; break;
        case 3: src = w3; break; case 4: src = w4; break; case 5: src = w5; break;
        default: src = w6; break;
    }
    wt[gid] = f2bf(src[(kt * 32 + quad * 8 + j) * 128 + nt * 16 + l15]);
}

// ---------------- CSR pass A: per-chunk coarse histogram (LDS atomics only)
__global__ __launch_bounds__(256) void k_chist(const int* __restrict__ ei, int* __restrict__ G) {
    __shared__ int h[NBUCK];
    int tid = threadIdx.x, blk = blockIdx.x;
    for (int b = tid; b < NBUCK; b += 256) h[b] = 0;
    __syncthreads();
    int e0 = blk * CHUNK;
    #pragma unroll 5
    for (int it = 0; it < 25; ++it) {
        int r = it * 256 + tid;
        if (r < CHUNK) {
            int dst = ei[N_EDGESC + e0 + r];
            atomicAdd(&h[dst >> 8], 1);
        }
    }
    __syncthreads();
    for (int b = tid; b < NBUCK; b += 256) G[b * 256 + blk] = h[b];
}

// ---------------- CSR pass B1: bucket totals + exclusive scan -> colbase[392]
__global__ __launch_bounds__(256) void k_csum(const int* __restrict__ G, int* __restrict__ colbase,
                                              int* __restrict__ offs) {
    __shared__ int t[NBUCK + 1];
    int tid = threadIdx.x;
    for (int b = tid; b < NBUCK; b += 256) {
        int s = 0;
        const int* col = G + b * 256;
        #pragma unroll 8
        for (int i = 0; i < 256; ++i) s += col[i];
        t[b] = s;
    }
    __syncthreads();
    if (tid < 64) {
        int lane = tid;
        int loc[7];
        int s = 0;
        #pragma unroll
        for (int j = 0; j < 7; ++j) {
            int idx = lane * 7 + j;
            loc[j] = (idx < NBUCK) ? t[idx] : 0;
            s += loc[j];
        }
        int incl = s;
        #pragma unroll
        for (int d = 1; d < 64; d <<= 1) { int tt = __shfl_up(incl, d, 64); if (lane >= d) incl += tt; }
        int run = incl - s;
        #pragma unroll
        for (int j = 0; j < 7; ++j) {
            int idx = lane * 7 + j;
            if (idx < NBUCK + 1) t[idx] = run;
            run += loc[j];
        }
    }
    __syncthreads();
    for (int b = tid; b < NBUCK + 1; b += 256) colbase[b] = t[b];
    if (tid == 0) offs[N_NODESC] = N_EDGESC;
}

// ---------------- CSR pass B2: per-bucket column scan -> Base[bucket][block]
__global__ __launch_bounds__(256) void k_base(const int* __restrict__ G, const int* __restrict__ colbase,
                                              int* __restrict__ Base) {
    __shared__ int wsum[4];
    int b = blockIdx.x;
    int tid = threadIdx.x;
    int lane = tid & 63, wid = tid >> 6;
    int v = G[b * 256 + tid];
    int incl = v;
    #pragma unroll
    for (int d = 1; d < 64; d <<= 1) { int tt = __shfl_up(incl, d, 64); if (lane >= d) incl += tt; }
    if (lane == 63) wsum[wid] = incl;
    __syncthreads();
    if (tid == 0) { int s = 0; for (int k = 0; k < 4; ++k) { int tt = wsum[k]; wsum[k] = s; s += tt; } }
    __syncthreads();
    Base[b * 256 + tid] = colbase[b] + wsum[wid] + incl - v;
}

// ---------------- CSR pass C: bucket-grouped scatter of packed 8B records (LDS cursors)
__global__ __launch_bounds__(256) void k_part(const int* __restrict__ ei, const float* __restrict__ ew,
                                              const int* __restrict__ Base, int2* __restrict__ tmp) {
    __shared__ int cur[NBUCK];
    int tid = threadIdx.x, blk = blockIdx.x;
    for (int b = tid; b < NBUCK; b += 256) cur[b] = Base[b * 256 + blk];
    __syncthreads();
    int e0 = blk * CHUNK;
    for (int it = 0; it < 25; ++it) {
        int r = it * 256 + tid;
        if (r < CHUNK) {
            int e = e0 + r;
            int src = ei[e];
            int dst = ei[N_EDGESC + e];
            float w = ew[e];
            int pos = atomicAdd(&cur[dst >> 8], 1);
            tmp[pos] = make_int2(src | ((dst & 255) << 17), __float_as_int(w));
        }
    }
}

// ---------------- CSR pass D: per-bucket fine counting sort entirely in LDS
__global__ __launch_bounds__(256) void k_fine(const int2* __restrict__ tmp, const int* __restrict__ colbase,
                                              int* __restrict__ offs, int2* __restrict__ edges) {
    __shared__ int2 recs[CAPB];
    __shared__ int hist[256];
    __shared__ int cur[256];
    __shared__ int wsum[4];
    int tid = threadIdx.x, b = blockIdx.x;
    int start = colbase[b], end = colbase[b + 1];
    int size = end - start;
    bool staged = (size <= CAPB);
    hist[tid] = 0;
    __syncthreads();
    for (int i = tid; i < size; i += 256) {
        int2 r = tmp[start + i];
        if (staged) recs[i] = r;
        atomicAdd(&hist[(r.x >> 17) & 255], 1);
    }
    __syncthreads();
    int lane = tid & 63, wid = tid >> 6;
    int v = hist[tid];
    int incl = v;
    #pragma unroll
    for (int d = 1; d < 64; d <<= 1) { int tt = __shfl_up(incl, d, 64); if (lane >= d) incl += tt; }
    if (lane == 63) wsum[wid] = incl;
    __syncthreads();
    if (tid == 0) { int s = 0; for (int k = 0; k < 4; ++k) { int tt = wsum[k]; wsum[k] = s; s += tt; } }
    __syncthreads();
    int excl = wsum[wid] + incl - v;
    cur[tid] = excl;
    int node = b * 256 + tid;
    if (node < N_NODESC) offs[node] = start + excl;
    __syncthreads();
    for (int i = tid; i < size; i += 256) {
        int2 r = staged ? recs[i] : tmp[start + i];
        int f = (r.x >> 17) & 255;
        int p = atomicAdd(&cur[f], 1);
        edges[start + p] = make_int2(r.x & 0x1FFFF, r.y);
    }
}

// ---------------- aggregation: HALF-WAVE per node (2 nodes/wave) -- round-1 structure (57 us)
__global__ __launch_bounds__(256) void k_agg(const unsigned short* __restrict__ hbf, const int* __restrict__ offs,
                                             const int2* __restrict__ edges, unsigned short* __restrict__ xnbf) {
    int tid = threadIdx.x;
    int q = tid & 15;
    int sub = (tid >> 4) & 1;
    int n = blockIdx.x * 8 + (tid >> 5);
    int s = offs[n], e = offs[n + 1];
    float acc[8] = {};
    float wsum = 0.f;
    for (int j = s; j < e; j += 8) {
        int idx[4];
        bool pr[4];
        int2 rec[4];
        #pragma unroll
        for (int u = 0; u < 4; ++u) {
            idx[u] = j + u * 2 + sub;
            pr[u] = idx[u] < e;
            rec[u] = edges[pr[u] ? idx[u] : s];
        }
        uint4 v[4];
        float w[4];
        #pragma unroll
        for (int u = 0; u < 4; ++u) {
            w[u] = pr[u] ? __int_as_float(rec[u].y) : 0.f;
            v[u] = *(const uint4*)(hbf + (size_t)rec[u].x * 128 + q * 8);
        }
        #pragma unroll
        for (int u = 0; u < 4; ++u) {
            unsigned uu[4] = {v[u].x, v[u].y, v[u].z, v[u].w};
            #pragma unroll
            for (int k = 0; k < 4; ++k) {
                acc[2 * k]     += w[u] * asf(uu[k] << 16);
                acc[2 * k + 1] += w[u] * asf(uu[k] & 0xffff0000u);
            }
            wsum += w[u];
        }
    }
    #pragma unroll
    for (int k = 0; k < 8; ++k) acc[k] += __shfl_xor(acc[k], 16, 64);
    wsum += __shfl_xor(wsum, 16, 64);
    float inv = 1.f / fmaxf(wsum, 1.f);
    if (((tid >> 4) & 1) == 0) {
        unsigned o[4];
        #pragma unroll
        for (int k = 0; k < 4; ++k)
            o[k] = (unsigned)f2bf(acc[2 * k] * inv) | ((unsigned)f2bf(acc[2 * k + 1] * inv) << 16);
        *(uint4*)(xnbf + (size_t)n * 128 + q * 8) = make_uint4(o[0], o[1], o[2], o[3]);
    }
}

// ---------------- input GEMM: hbf = bf16(relu(x @ W_in + b)); W staged in LDS once/block,
// tile aliases the weight LDS after MFMA (round-1 structure, 3 blocks/CU).
__global__ __launch_bounds__(256, 3) void k_gemm_in(const float* __restrict__ X,
                                                    const unsigned short* __restrict__ WF,
                                                    const float* __restrict__ bias,
                                                    unsigned short* __restrict__ Hbf, int M) {
    __shared__ unsigned short smem[128 * TPAD];
    int tid = threadIdx.x;
    int lane = tid & 63;
    int wid = tid >> 6;
    int l15 = lane & 15;
    int quad = lane >> 4;
    #pragma unroll
    for (int it = 0; it < 8; ++it) {
        int idx = (it * 256 + tid) * 8;
        *(uint4*)(smem + idx) = *(const uint4*)(WF + idx);
    }
    int rowbase = blockIdx.x * 128 + wid * 32;
    bf16x8 a[2][4];
    #pragma unroll
    for (int rs = 0; rs < 2; ++rs) {
        int ra = min(rowbase + rs * 16 + l15, M - 1);
        float buf[4][8];
        #pragma unroll
        for (int kt = 0; kt < 4; ++kt) {
            int k0 = kt * 32 + quad * 8;
            *(float4*)(buf[kt])     = *(const float4*)(X + (size_t)ra * 128 + k0);
            *(float4*)(buf[kt] + 4) = *(const float4*)(X + (size_t)ra * 128 + k0 + 4);
        }
        #pragma unroll
        for (int kt = 0; kt < 4; ++kt) a[rs][kt] = pack8(buf[kt]);
    }
    __syncthreads();
    f32x4 acc[2][8] = {};
    #pragma unroll
    for (int kt = 0; kt < 4; ++kt) {
        #pragma unroll
        for (int nt = 0; nt < 8; ++nt) {
            bf16x8 b = *(const bf16x8*)(smem + ((kt * 8 + nt) * 64 + lane) * 8);
            #pragma unroll
            for (int rs = 0; rs < 2; ++rs)
                acc[rs][nt] = __builtin_amdgcn_mfma_f32_16x16x32_bf16(a[rs][kt], b, acc[rs][nt], 0, 0, 0);
        }
    }
    __syncthreads();
    #pragma unroll
    for (int nt = 0; nt < 8; ++nt) {
        int c = nt * 16 + l15;
        float bv = bias[c];
        #pragma unroll
        for (int rs = 0; rs < 2; ++rs) {
            #pragma unroll
            for (int i = 0; i < 4; ++i) {
                int rl = wid * 32 + rs * 16 + quad * 4 + i;
                float v = fmaxf(acc[rs][nt][i] + bv, 0.f);
                smem[rl * TPAD + c] = f2bf(v);
            }
        }
    }
    __syncthreads();
    int rl = tid >> 1;
    int cs = (tid & 1) * 64;
    int gr = blockIdx.x * 128 + rl;
    if (gr < M) {
        #pragma unroll
        for (int k = 0; k < 8; ++k) {
            uint4 v = *(const uint4*)(smem + rl * TPAD + cs + k * 8);
            *(uint4*)(Hbf + (size_t)gr * 128 + cs + k * 8) = v;
        }
    }
}

// ---------------- FUSED layer GEMM + BN + residual, single kernel with in-grid barrier.
// Phase 1: tile = h@Ws + xn@Wn + bias in LDS; column sum/sumsq -> global atomics.
// Barrier: arrive-and-spin on device counter (447 blocks <= guaranteed 512 co-resident).
// Phase 2: scale/shift from completed stats; BN+ReLU+residual applied from LDS tile.
template <int RELU, int FINAL>
__global__ __launch_bounds__(448, 4) void k_gemm_bn(const unsigned short* Abf,
                                                    const unsigned short* __restrict__ Xbf,
                                                    const unsigned short* __restrict__ WsF,
                                                    const unsigned short* __restrict__ WnF,
                                                    const float* __restrict__ bs, const float* __restrict__ bn,
                                                    const float* __restrict__ gma, const float* __restrict__ bta,
                                                    unsigned short* Hbf, float* __restrict__ Out,
                                                    float* colsum, float* colsq, int* ctr, int M) {
    __shared__ unsigned short smem[32768];   // Ws[0..16384)+Wn[16384..32768); tile (224*136=30464) aliases after MFMA
    __shared__ float s_sum[128];
    __shared__ float s_sq[128];
    int tid = threadIdx.x;
    if (tid < 128) { s_sum[tid] = 0.f; s_sq[tid] = 0.f; }
    // stage both weight matrices (448 threads x 8 shorts, strided)
    for (int idx = tid * 8; idx < 16384; idx += 448 * 8) {
        *(uint4*)(smem + idx)         = *(const uint4*)(WsF + idx);
        *(uint4*)(smem + 16384 + idx) = *(const uint4*)(WnF + idx);
    }
    int lane = tid & 63;
    int wid = tid >> 6;                    // 0..6
    int l15 = lane & 15;
    int quad = lane >> 4;
    int rowbase = blockIdx.x * FROWS + wid * 32;
    bf16x8 ah[2][4], ax[2][4];
    #pragma unroll
    for (int rs = 0; rs < 2; ++rs) {
        int ra = min(rowbase + rs * 16 + l15, M - 1);
        #pragma unroll
        for (int kt = 0; kt < 4; ++kt) {
            int k0 = kt * 32 + quad * 8;
            ah[rs][kt] = *(const bf16x8*)(Abf + (size_t)ra * 128 + k0);
            ax[rs][kt] = *(const bf16x8*)(Xbf + (size_t)ra * 128 + k0);
        }
    }
    __syncthreads();
    f32x4 acc[2][8] = {};
    #pragma unroll
    for (int kt = 0; kt < 4; ++kt) {
        #pragma unroll
        for (int nt = 0; nt < 8; ++nt) {
            int fo = ((kt * 8 + nt) * 64 + lane) * 8;
            bf16x8 bsv = *(const bf16x8*)(smem + fo);
            bf16x8 bnv = *(const bf16x8*)(smem + 16384 + fo);
            #pragma unroll
            for (int rs = 0; rs < 2; ++rs) {
                acc[rs][nt] = __builtin_amdgcn_mfma_f32_16x16x32_bf16(ah[rs][kt], bsv, acc[rs][nt], 0, 0, 0);
                acc[rs][nt] = __builtin_amdgcn_mfma_f32_16x16x32_bf16(ax[rs][kt], bnv, acc[rs][nt], 0, 0, 0);
            }
        }
    }
    __syncthreads();   // weights dead; tile aliases them
    #pragma unroll
    for (int nt = 0; nt < 8; ++nt) {
        int c = nt * 16 + l15;
        float bv = bs[c] + bn[c];
        float ps = 0.f, pq = 0.f;
        #pragma unroll
        for (int rs = 0; rs < 2; ++rs) {
            #pragma unroll
            for (int i = 0; i < 4; ++i) {
                int rl = wid * 32 + rs * 16 + quad * 4 + i;   // local row 0..223
                int r = blockIdx.x * FROWS + rl;
                float v = acc[rs][nt][i] + bv;
                if (r < M) {
                    unsigned short qv = f2bf(v);
                    smem[rl * TPAD + c] = qv;
                    float vq = asf((unsigned)qv << 16);
                    ps += vq; pq += vq * vq;
                }
            }
        }
        ps += __shfl_xor(ps, 16); pq += __shfl_xor(pq, 16);
        ps += __shfl_xor(ps, 32); pq += __shfl_xor(pq, 32);
        if (quad == 0) { atomicAdd(&s_sum[c], ps); atomicAdd(&s_sq[c], pq); }
    }
    __syncthreads();
    if (tid < 128) atomicAdd(&colsum[tid], s_sum[tid]);
    else if (tid < 256) atomicAdd(&colsq[tid - 128], s_sq[tid - 128]);
    // ---- grid barrier: every thread fences, block arrives once, tid0 spins
    __threadfence();
    __syncthreads();
    if (tid == 0) {
        atomicAdd(ctr, 1);
        long long fuel = 2000000000LL;
        while (__hip_atomic_load(ctr, __ATOMIC_ACQUIRE, __HIP_MEMORY_SCOPE_AGENT) < FB && --fuel > 0)
            __builtin_amdgcn_s_sleep(8);
    }
    __syncthreads();
    // ---- per-column scale/shift from completed global stats (agent-scope loads bypass L1)
    const float invM = 1.0f / (float)N_NODESC;
    if (tid < 128) {
        float su = __hip_atomic_load(&colsum[tid], __ATOMIC_RELAXED, __HIP_MEMORY_SCOPE_AGENT);
        float sq = __hip_atomic_load(&colsq[tid], __ATOMIC_RELAXED, __HIP_MEMORY_SCOPE_AGENT);
        float mu = su * invM;
        float var = sq * invM - mu * mu;
        float is = rsqrtf(var + 1e-5f);
        float sc = is * gma[tid];
        s_sum[tid] = sc;                   // scale
        s_sq[tid]  = bta[tid] - mu * sc;   // shift
    }
    __syncthreads();
    // ---- apply BN + (ReLU) + residual from LDS tile; write hbf (bf16) or Out (fp32)
    int rl = tid >> 1;                     // 0..223
    int cs = (tid & 1) * 64;
    int gr = blockIdx.x * FROWS + rl;
    if (gr < M) {
        #pragma unroll
        for (int k = 0; k < 8; ++k) {
            int c0 = cs + k * 8;
            uint4 tv = *(const uint4*)(smem + rl * TPAD + c0);
            uint4 hv = *(const uint4*)(Hbf + (size_t)gr * 128 + c0);
            unsigned tw[4] = {tv.x, tv.y, tv.z, tv.w};
            unsigned hw[4] = {hv.x, hv.y, hv.z, hv.w};
            float r[8];
            #pragma unroll
            for (int p = 0; p < 4; ++p) {
                int ca = c0 + 2 * p, cb = c0 + 2 * p + 1;
                float ta = asf(tw[p] << 16);
                float tb = asf(tw[p] & 0xffff0000u);
                float va = ta * s_sum[ca] + s_sq[ca];
                float vb = tb * s_sum[cb] + s_sq[cb];
                if (RELU) { va = fmaxf(va, 0.f); vb = fmaxf(vb, 0.f); }
                r[2 * p]     = asf(hw[p] << 16) + va;
                r[2 * p + 1] = asf(hw[p] & 0xffff0000u) + vb;
            }
            if (FINAL) {
                *(float4*)(Out + (size_t)gr * 128 + c0)     = make_float4(r[0], r[1], r[2], r[3]);
                *(float4*)(Out + (size_t)gr * 128 + c0 + 4) = make_float4(r[4], r[5], r[6], r[7]);
            } else {
                unsigned o[4];
                #pragma unroll
                for (int p = 0; p < 4; ++p)
                    o[p] = (unsigned)f2bf(r[2 * p]) | ((unsigned)f2bf(r[2 * p + 1]) << 16);
                *(uint4*)(Hbf + (size_t)gr * 128 + c0) = make_uint4(o[0], o[1], o[2], o[3]);
            }
        }
    }
}

// ---------------- host
static inline size_t al256(size_t x) { return (x + 255) & ~(size_t)255; }

extern "C" void kernel_launch(void* const* d_in, const int* in_sizes, int n_in,
                              void* d_out, int out_size, void* d_ws, size_t ws_size,
                              hipStream_t stream) {
    const float* x    = (const float*)d_in[0];
    const int*   ei   = (const int*)d_in[1];
    const float* ew   = (const float*)d_in[2];
    const float* W_in = (const float*)d_in[3];
    const float* b_in = (const float*)d_in[4];
    const float* Ws[3] = {(const float*)d_in[5],  (const float*)d_in[11], (const float*)d_in[17]};
    const float* bs[3] = {(const float*)d_in[6],  (const float*)d_in[12], (const float*)d_in[18]};
    const float* Wn[3] = {(const float*)d_in[7],  (const float*)d_in[13], (const float*)d_in[19]};
    const float* bn[3] = {(const float*)d_in[8],  (const float*)d_in[14], (const float*)d_in[20]};
    const float* g[3]  = {(const float*)d_in[9],  (const float*)d_in[15], (const float*)d_in[21]};
    const float* be[3] = {(const float*)d_in[10], (const float*)d_in[16], (const float*)d_in[22]};

    char* ws = (char*)d_ws;
    size_t off = 0;
    const size_t nElem = (size_t)N_NODESC * DIM;          // 12.8M
    unsigned short* hbf    = (unsigned short*)(ws + off); off = al256(off + nElem * 2);
    unsigned short* xnbf   = (unsigned short*)(ws + off); off = al256(off + nElem * 2);
    int2*           tmp    = (int2*)(ws + off);           off = al256(off + (size_t)N_EDGESC * 8);
    unsigned short* wt     = (unsigned short*)(ws + off); off = al256(off + 7 * 16384 * 2);
    int*            offs   = (int*)(ws + off);            off = al256(off + ((size_t)N_NODESC + 1) * 4);
    int2*           edges  = (int2*)(ws + off);           off = al256(off + (size_t)N_EDGESC * 8 + 64);
    int*            G      = (int*)(ws + off);            off = al256(off + (size_t)NBUCK * 256 * 4);
    int*            Base   = (int*)(ws + off);            off = al256(off + (size_t)NBUCK * 256 * 4);
    int*            colbase= (int*)(ws + off);            off = al256(off + (size_t)(NBUCK + 1) * 4);
    float*          stats  = (float*)(ws + off);          off = al256(off + 3 * 256 * 4 + 256);
    int*            ctrs   = (int*)(stats + 3 * 256);     // 3 barrier counters, memset with stats

    (void)hipMemsetAsync(stats, 0, 3 * 256 * 4 + 256, stream);

    k_wcvt<<<448, 256, 0, stream>>>(W_in, Ws[0], Wn[0], Ws[1], Wn[1], Ws[2], Wn[2], wt);

    // atomic-free CSR build (two-level counting sort)
    k_chist<<<CSBLK, 256, 0, stream>>>(ei, G);
    k_csum<<<1, 256, 0, stream>>>(G, colbase, offs);
    k_base<<<NBUCK, 256, 0, stream>>>(G, colbase, Base);
    k_part<<<CSBLK, 256, 0, stream>>>(ei, ew, Base, tmp);
    k_fine<<<NBUCK, 256, 0, stream>>>(tmp, colbase, offs, edges);

    k_gemm_in<<<GB, 256, 0, stream>>>(x, wt, b_in, hbf, N_NODESC);

    for (int l = 0; l < 3; ++l) {
        k_agg<<<12500, 256, 0, stream>>>(hbf, offs, edges, xnbf);
        if (l < 2)
            k_gemm_bn<1, 0><<<FB, 448, 0, stream>>>(hbf, xnbf,
                                                    wt + (size_t)(1 + 2 * l) * 16384,
                                                    wt + (size_t)(2 + 2 * l) * 16384,
                                                    bs[l], bn[l], g[l], be[l],
                                                    hbf, nullptr,
                                                    stats + l * 256, stats + l * 256 + 128,
                                                    ctrs + l, N_NODESC);
        else
            k_gemm_bn<0, 1><<<FB, 448, 0, stream>>>(hbf, xnbf,
                                                    wt + (size_t)(1 + 2 * l) * 16384,
                                                    wt + (size_t)(2 + 2 * l) * 16384,
                                                    bs[l], bn[l], g[l], be[l],
                                                    hbf, (float*)d_out,
                                                    stats + l * 256, stats + l * 256 + 128,
                                                    ctrs + l, N_NODESC);
    }
}

// Round 8
// 686.363 us; speedup vs baseline: 1.0823x; 1.0823x over previous
//
#include <hip/hip_runtime.h>

#define N_NODESC 100000
#define N_EDGESC 1600000
#define DIM 128
#define GB 782        // ceil(100000 / 128) gemm_in blocks
#define TPAD 136      // LDS tile row stride in shorts

// ---- fused gemm+bn geometry: 391 blocks x 256 threads, 256 rows/block (2 subtiles of 128).
// launch_bounds(256,2) -> VGPR budget 256 (no spill); LDS 66.5KB -> 2 blocks/CU;
// capacity 512 >= 391 -> grid barrier is deadlock-free.
#define FB 391

// ---- counting-sort CSR build geometry
#define NBUCK 391     // ceil(100000 / 256) coarse buckets (256 nodes each)
#define CSBLK 256     // chunk blocks
#define CHUNK 6250    // edges per chunk block (256 * 6250 = 1.6M exactly)
#define CAPB  6144    // LDS staging capacity per bucket (expect max ~4400)

typedef __bf16 bf16x8 __attribute__((ext_vector_type(8)));
typedef unsigned short u16x8 __attribute__((ext_vector_type(8)));
typedef float f32x4 __attribute__((ext_vector_type(4)));

__device__ __forceinline__ float asf(unsigned u) { return __uint_as_float(u); }
__device__ __forceinline__ unsigned short f2bf(float f) {
    unsigned u = __float_as_uint(f);
    u += 0x7fffu + ((u >> 16) & 1u);
    return (unsigned short)(u >> 16);
}
__device__ __forceinline__ bf16x8 pack8(const float* f) {
    u16x8 u;
    #pragma unroll
    for (int i = 0; i < 8; ++i) u[i] = f2bf(f[i]);
    return __builtin_bit_cast(bf16x8, u);
}

// ---------------- weight convert: 7 matrices fp32 [k][c] -> bf16 FRAGMENT-MAJOR:
// linear index = ((kt*8 + nt)*64 + lane)*8 + j  maps to  W[(kt*32 + quad*8 + j)*128 + nt*16 + l15]
__global__ __launch_bounds__(256) void k_wcvt(const float* __restrict__ w0, const float* __restrict__ w1,
                                              const float* __restrict__ w2, const float* __restrict__ w3,
                                              const float* __restrict__ w4, const float* __restrict__ w5,
                                              const float* __restrict__ w6, unsigned short* __restrict__ wt) {
    int gid = blockIdx.x * 256 + threadIdx.x;   // 0..114687
    int m = gid >> 14;
    int r = gid & 16383;
    int j = r & 7;
    int lane = (r >> 3) & 63;
    int nt = (r >> 9) & 7;
    int kt = (r >> 12) & 3;
    int quad = lane >> 4;
    int l15 = lane & 15;
    const float* src;
    switch (m) {
        case 0: src = w0; break; case 1: src = w1; break; case 2: src = w2; break;
        case 3: src = w3; break; case 4: src = w4; break; case 5: src = w5; break;
        default: src = w6; break;
    }
    wt[gid] = f2bf(src[(kt * 32 + quad * 8 + j) * 128 + nt * 16 + l15]);
}

// ---------------- CSR pass A: per-chunk coarse histogram (LDS atomics only)
__global__ __launch_bounds__(256) void k_chist(const int* __restrict__ ei, int* __restrict__ G) {
    __shared__ int h[NBUCK];
    int tid = threadIdx.x, blk = blockIdx.x;
    for (int b = tid; b < NBUCK; b += 256) h[b] = 0;
    __syncthreads();
    int e0 = blk * CHUNK;
    #pragma unroll 5
    for (int it = 0; it < 25; ++it) {
        int r = it * 256 + tid;
        if (r < CHUNK) {
            int dst = ei[N_EDGESC + e0 + r];
            atomicAdd(&h[dst >> 8], 1);
        }
    }
    __syncthreads();
    for (int b = tid; b < NBUCK; b += 256) G[b * 256 + blk] = h[b];
}

// ---------------- CSR pass B1: bucket totals + exclusive scan -> colbase[392]
__global__ __launch_bounds__(256) void k_csum(const int* __restrict__ G, int* __restrict__ colbase,
                                              int* __restrict__ offs) {
    __shared__ int t[NBUCK + 1];
    int tid = threadIdx.x;
    for (int b = tid; b < NBUCK; b += 256) {
        int s = 0;
        const int* col = G + b * 256;
        #pragma unroll 8
        for (int i = 0; i < 256; ++i) s += col[i];
        t[b] = s;
    }
    __syncthreads();
    if (tid < 64) {
        int lane = tid;
        int loc[7];
        int s = 0;
        #pragma unroll
        for (int j = 0; j < 7; ++j) {
            int idx = lane * 7 + j;
            loc[j] = (idx < NBUCK) ? t[idx] : 0;
            s += loc[j];
        }
        int incl = s;
        #pragma unroll
        for (int d = 1; d < 64; d <<= 1) { int tt = __shfl_up(incl, d, 64); if (lane >= d) incl += tt; }
        int run = incl - s;
        #pragma unroll
        for (int j = 0; j < 7; ++j) {
            int idx = lane * 7 + j;
            if (idx < NBUCK + 1) t[idx] = run;
            run += loc[j];
        }
    }
    __syncthreads();
    for (int b = tid; b < NBUCK + 1; b += 256) colbase[b] = t[b];
    if (tid == 0) offs[N_NODESC] = N_EDGESC;
}

// ---------------- CSR pass B2: per-bucket column scan -> Base[bucket][block]
__global__ __launch_bounds__(256) void k_base(const int* __restrict__ G, const int* __restrict__ colbase,
                                              int* __restrict__ Base) {
    __shared__ int wsum[4];
    int b = blockIdx.x;
    int tid = threadIdx.x;
    int lane = tid & 63, wid = tid >> 6;
    int v = G[b * 256 + tid];
    int incl = v;
    #pragma unroll
    for (int d = 1; d < 64; d <<= 1) { int tt = __shfl_up(incl, d, 64); if (lane >= d) incl += tt; }
    if (lane == 63) wsum[wid] = incl;
    __syncthreads();
    if (tid == 0) { int s = 0; for (int k = 0; k < 4; ++k) { int tt = wsum[k]; wsum[k] = s; s += tt; } }
    __syncthreads();
    Base[b * 256 + tid] = colbase[b] + wsum[wid] + incl - v;
}

// ---------------- CSR pass C: bucket-grouped scatter of packed 8B records (LDS cursors)
__global__ __launch_bounds__(256) void k_part(const int* __restrict__ ei, const float* __restrict__ ew,
                                              const int* __restrict__ Base, int2* __restrict__ tmp) {
    __shared__ int cur[NBUCK];
    int tid = threadIdx.x, blk = blockIdx.x;
    for (int b = tid; b < NBUCK; b += 256) cur[b] = Base[b * 256 + blk];
    __syncthreads();
    int e0 = blk * CHUNK;
    for (int it = 0; it < 25; ++it) {
        int r = it * 256 + tid;
        if (r < CHUNK) {
            int e = e0 + r;
            int src = ei[e];
            int dst = ei[N_EDGESC + e];
            float w = ew[e];
            int pos = atomicAdd(&cur[dst >> 8], 1);
            tmp[pos] = make_int2(src | ((dst & 255) << 17), __float_as_int(w));
        }
    }
}

// ---------------- CSR pass D: per-bucket fine counting sort entirely in LDS
__global__ __launch_bounds__(256) void k_fine(const int2* __restrict__ tmp, const int* __restrict__ colbase,
                                              int* __restrict__ offs, int2* __restrict__ edges) {
    __shared__ int2 recs[CAPB];
    __shared__ int hist[256];
    __shared__ int cur[256];
    __shared__ int wsum[4];
    int tid = threadIdx.x, b = blockIdx.x;
    int start = colbase[b], end = colbase[b + 1];
    int size = end - start;
    bool staged = (size <= CAPB);
    hist[tid] = 0;
    __syncthreads();
    for (int i = tid; i < size; i += 256) {
        int2 r = tmp[start + i];
        if (staged) recs[i] = r;
        atomicAdd(&hist[(r.x >> 17) & 255], 1);
    }
    __syncthreads();
    int lane = tid & 63, wid = tid >> 6;
    int v = hist[tid];
    int incl = v;
    #pragma unroll
    for (int d = 1; d < 64; d <<= 1) { int tt = __shfl_up(incl, d, 64); if (lane >= d) incl += tt; }
    if (lane == 63) wsum[wid] = incl;
    __syncthreads();
    if (tid == 0) { int s = 0; for (int k = 0; k < 4; ++k) { int tt = wsum[k]; wsum[k] = s; s += tt; } }
    __syncthreads();
    int excl = wsum[wid] + incl - v;
    cur[tid] = excl;
    int node = b * 256 + tid;
    if (node < N_NODESC) offs[node] = start + excl;
    __syncthreads();
    for (int i = tid; i < size; i += 256) {
        int2 r = staged ? recs[i] : tmp[start + i];
        int f = (r.x >> 17) & 255;
        int p = atomicAdd(&cur[f], 1);
        edges[start + p] = make_int2(r.x & 0x1FFFF, r.y);
    }
}

// ---------------- aggregation: HALF-WAVE per node (2 nodes/wave) -- round-1 structure (57 us)
__global__ __launch_bounds__(256) void k_agg(const unsigned short* __restrict__ hbf, const int* __restrict__ offs,
                                             const int2* __restrict__ edges, unsigned short* __restrict__ xnbf) {
    int tid = threadIdx.x;
    int q = tid & 15;
    int sub = (tid >> 4) & 1;
    int n = blockIdx.x * 8 + (tid >> 5);
    int s = offs[n], e = offs[n + 1];
    float acc[8] = {};
    float wsum = 0.f;
    for (int j = s; j < e; j += 8) {
        int idx[4];
        bool pr[4];
        int2 rec[4];
        #pragma unroll
        for (int u = 0; u < 4; ++u) {
            idx[u] = j + u * 2 + sub;
            pr[u] = idx[u] < e;
            rec[u] = edges[pr[u] ? idx[u] : s];
        }
        uint4 v[4];
        float w[4];
        #pragma unroll
        for (int u = 0; u < 4; ++u) {
            w[u] = pr[u] ? __int_as_float(rec[u].y) : 0.f;
            v[u] = *(const uint4*)(hbf + (size_t)rec[u].x * 128 + q * 8);
        }
        #pragma unroll
        for (int u = 0; u < 4; ++u) {
            unsigned uu[4] = {v[u].x, v[u].y, v[u].z, v[u].w};
            #pragma unroll
            for (int k = 0; k < 4; ++k) {
                acc[2 * k]     += w[u] * asf(uu[k] << 16);
                acc[2 * k + 1] += w[u] * asf(uu[k] & 0xffff0000u);
            }
            wsum += w[u];
        }
    }
    #pragma unroll
    for (int k = 0; k < 8; ++k) acc[k] += __shfl_xor(acc[k], 16, 64);
    wsum += __shfl_xor(wsum, 16, 64);
    float inv = 1.f / fmaxf(wsum, 1.f);
    if (((tid >> 4) & 1) == 0) {
        unsigned o[4];
        #pragma unroll
        for (int k = 0; k < 4; ++k)
            o[k] = (unsigned)f2bf(acc[2 * k] * inv) | ((unsigned)f2bf(acc[2 * k + 1] * inv) << 16);
        *(uint4*)(xnbf + (size_t)n * 128 + q * 8) = make_uint4(o[0], o[1], o[2], o[3]);
    }
}

// ---------------- input GEMM: hbf = bf16(relu(x @ W_in + b)); W staged in LDS once/block,
// tile aliases the weight LDS after MFMA (round-1 structure, 3 blocks/CU).
__global__ __launch_bounds__(256, 3) void k_gemm_in(const float* __restrict__ X,
                                                    const unsigned short* __restrict__ WF,
                                                    const float* __restrict__ bias,
                                                    unsigned short* __restrict__ Hbf, int M) {
    __shared__ unsigned short smem[128 * TPAD];
    int tid = threadIdx.x;
    int lane = tid & 63;
    int wid = tid >> 6;
    int l15 = lane & 15;
    int quad = lane >> 4;
    #pragma unroll
    for (int it = 0; it < 8; ++it) {
        int idx = (it * 256 + tid) * 8;
        *(uint4*)(smem + idx) = *(const uint4*)(WF + idx);
    }
    int rowbase = blockIdx.x * 128 + wid * 32;
    bf16x8 a[2][4];
    #pragma unroll
    for (int rs = 0; rs < 2; ++rs) {
        int ra = min(rowbase + rs * 16 + l15, M - 1);
        float buf[4][8];
        #pragma unroll
        for (int kt = 0; kt < 4; ++kt) {
            int k0 = kt * 32 + quad * 8;
            *(float4*)(buf[kt])     = *(const float4*)(X + (size_t)ra * 128 + k0);
            *(float4*)(buf[kt] + 4) = *(const float4*)(X + (size_t)ra * 128 + k0 + 4);
        }
        #pragma unroll
        for (int kt = 0; kt < 4; ++kt) a[rs][kt] = pack8(buf[kt]);
    }
    __syncthreads();
    f32x4 acc[2][8] = {};
    #pragma unroll
    for (int kt = 0; kt < 4; ++kt) {
        #pragma unroll
        for (int nt = 0; nt < 8; ++nt) {
            bf16x8 b = *(const bf16x8*)(smem + ((kt * 8 + nt) * 64 + lane) * 8);
            #pragma unroll
            for (int rs = 0; rs < 2; ++rs)
                acc[rs][nt] = __builtin_amdgcn_mfma_f32_16x16x32_bf16(a[rs][kt], b, acc[rs][nt], 0, 0, 0);
        }
    }
    __syncthreads();
    #pragma unroll
    for (int nt = 0; nt < 8; ++nt) {
        int c = nt * 16 + l15;
        float bv = bias[c];
        #pragma unroll
        for (int rs = 0; rs < 2; ++rs) {
            #pragma unroll
            for (int i = 0; i < 4; ++i) {
                int rl = wid * 32 + rs * 16 + quad * 4 + i;
                float v = fmaxf(acc[rs][nt][i] + bv, 0.f);
                smem[rl * TPAD + c] = f2bf(v);
            }
        }
    }
    __syncthreads();
    int rl = tid >> 1;
    int cs = (tid & 1) * 64;
    int gr = blockIdx.x * 128 + rl;
    if (gr < M) {
        #pragma unroll
        for (int k = 0; k < 8; ++k) {
            uint4 v = *(const uint4*)(smem + rl * TPAD + cs + k * 8);
            *(uint4*)(Hbf + (size_t)gr * 128 + cs + k * 8) = v;
        }
    }
}

// ---------------- FUSED layer GEMM + BN + residual (grid-barrier, spill-proof geometry).
// 256 threads, 2 sequential 128-row subtiles; GEMM results kept PACKED IN REGISTERS
// across the barrier (64 VGPRs); phase 2 replays the round-1 tile-transpose per subtile.
template <int RELU, int FINAL>
__global__ __launch_bounds__(256, 2) void k_gemm_bn(const unsigned short* Abf,
                                                    const unsigned short* __restrict__ Xbf,
                                                    const unsigned short* __restrict__ WsF,
                                                    const unsigned short* __restrict__ WnF,
                                                    const float* __restrict__ bs, const float* __restrict__ bn,
                                                    const float* __restrict__ gma, const float* __restrict__ bta,
                                                    unsigned short* Hbf, float* __restrict__ Out,
                                                    float* colsum, float* colsq, int* ctr, int M) {
    __shared__ unsigned short smem[32768];   // Ws[0..16384)+Wn[16384..32768); 128xTPAD tile aliases after MFMA
    __shared__ float s_a[128];               // stats sum -> later scale
    __shared__ float s_b[128];               // stats sumsq -> later shift
    int tid = threadIdx.x;
    if (tid < 128) { s_a[tid] = 0.f; s_b[tid] = 0.f; }
    #pragma unroll
    for (int it = 0; it < 8; ++it) {
        int idx = (it * 256 + tid) * 8;
        *(uint4*)(smem + idx)         = *(const uint4*)(WsF + idx);
        *(uint4*)(smem + 16384 + idx) = *(const uint4*)(WnF + idx);
    }
    int lane = tid & 63;
    int wid = tid >> 6;
    int l15 = lane & 15;
    int quad = lane >> 4;
    unsigned pk[2][8][2][2];   // [sub][nt][rs][half] packed bf16 pairs -- all indices static
    __syncthreads();           // weights staged + stats init
    #pragma unroll
    for (int sub = 0; sub < 2; ++sub) {
        int rowbase = blockIdx.x * 256 + sub * 128 + wid * 32;
        bf16x8 ah[2][4], ax[2][4];
        #pragma unroll
        for (int rs = 0; rs < 2; ++rs) {
            int ra = min(rowbase + rs * 16 + l15, M - 1);
            #pragma unroll
            for (int kt = 0; kt < 4; ++kt) {
                int k0 = kt * 32 + quad * 8;
                ah[rs][kt] = *(const bf16x8*)(Abf + (size_t)ra * 128 + k0);
                ax[rs][kt] = *(const bf16x8*)(Xbf + (size_t)ra * 128 + k0);
            }
        }
        f32x4 acc[2][8] = {};
        #pragma unroll
        for (int kt = 0; kt < 4; ++kt) {
            #pragma unroll
            for (int nt = 0; nt < 8; ++nt) {
                int fo = ((kt * 8 + nt) * 64 + lane) * 8;
                bf16x8 bsv = *(const bf16x8*)(smem + fo);
                bf16x8 bnv = *(const bf16x8*)(smem + 16384 + fo);
                #pragma unroll
                for (int rs = 0; rs < 2; ++rs) {
                    acc[rs][nt] = __builtin_amdgcn_mfma_f32_16x16x32_bf16(ah[rs][kt], bsv, acc[rs][nt], 0, 0, 0);
                    acc[rs][nt] = __builtin_amdgcn_mfma_f32_16x16x32_bf16(ax[rs][kt], bnv, acc[rs][nt], 0, 0, 0);
                }
            }
        }
        // bias + round to bf16, accumulate column stats, pack into registers
        #pragma unroll
        for (int nt = 0; nt < 8; ++nt) {
            int c = nt * 16 + l15;
            float bv = bs[c] + bn[c];
            float ps = 0.f, pq = 0.f;
            #pragma unroll
            for (int rs = 0; rs < 2; ++rs) {
                unsigned qv4[4];
                #pragma unroll
                for (int i = 0; i < 4; ++i) {
                    int r = rowbase + rs * 16 + quad * 4 + i;
                    unsigned short qv = f2bf(acc[rs][nt][i] + bv);
                    qv4[i] = qv;
                    if (r < M) {
                        float vq = asf((unsigned)qv << 16);
                        ps += vq; pq += vq * vq;
                    }
                }
                pk[sub][nt][rs][0] = qv4[0] | (qv4[1] << 16);
                pk[sub][nt][rs][1] = qv4[2] | (qv4[3] << 16);
            }
            ps += __shfl_xor(ps, 16); pq += __shfl_xor(pq, 16);
            ps += __shfl_xor(ps, 32); pq += __shfl_xor(pq, 32);
            if (quad == 0) { atomicAdd(&s_a[c], ps); atomicAdd(&s_b[c], pq); }
        }
    }
    __syncthreads();
    if (tid < 128) atomicAdd(&colsum[tid], s_a[tid]);
    else atomicAdd(&colsq[tid - 128], s_b[tid - 128]);
    // ---- grid barrier (391 blocks all co-resident)
    __threadfence();
    __syncthreads();
    if (tid == 0) {
        atomicAdd(ctr, 1);
        long long fuel = 2000000000LL;
        while (__hip_atomic_load(ctr, __ATOMIC_ACQUIRE, __HIP_MEMORY_SCOPE_AGENT) < FB && --fuel > 0)
            __builtin_amdgcn_s_sleep(8);
    }
    __syncthreads();
    // ---- per-column scale/shift from completed global stats
    const float invM = 1.0f / (float)N_NODESC;
    if (tid < 128) {
        float su = __hip_atomic_load(&colsum[tid], __ATOMIC_RELAXED, __HIP_MEMORY_SCOPE_AGENT);
        float sq = __hip_atomic_load(&colsq[tid], __ATOMIC_RELAXED, __HIP_MEMORY_SCOPE_AGENT);
        float mu = su * invM;
        float var = sq * invM - mu * mu;
        float is = rsqrtf(var + 1e-5f);
        float sc = is * gma[tid];
        s_a[tid] = sc;
        s_b[tid] = bta[tid] - mu * sc;
    }
    __syncthreads();
    // ---- phase 2: per subtile, dump packed results to LDS tile, then coalesced BN+residual
    #pragma unroll
    for (int sub = 0; sub < 2; ++sub) {
        #pragma unroll
        for (int nt = 0; nt < 8; ++nt) {
            int c = nt * 16 + l15;
            #pragma unroll
            for (int rs = 0; rs < 2; ++rs) {
                int rl = wid * 32 + rs * 16 + quad * 4;
                unsigned p0 = pk[sub][nt][rs][0], p1 = pk[sub][nt][rs][1];
                smem[(rl + 0) * TPAD + c] = (unsigned short)(p0 & 0xffff);
                smem[(rl + 1) * TPAD + c] = (unsigned short)(p0 >> 16);
                smem[(rl + 2) * TPAD + c] = (unsigned short)(p1 & 0xffff);
                smem[(rl + 3) * TPAD + c] = (unsigned short)(p1 >> 16);
            }
        }
        __syncthreads();
        int rl = tid >> 1;
        int cs = (tid & 1) * 64;
        int gr = blockIdx.x * 256 + sub * 128 + rl;
        if (gr < M) {
            #pragma unroll
            for (int k = 0; k < 8; ++k) {
                int c0 = cs + k * 8;
                uint4 tv = *(const uint4*)(smem + rl * TPAD + c0);
                uint4 hv = *(const uint4*)(Hbf + (size_t)gr * 128 + c0);
                unsigned tw[4] = {tv.x, tv.y, tv.z, tv.w};
                unsigned hw[4] = {hv.x, hv.y, hv.z, hv.w};
                float r[8];
                #pragma unroll
                for (int p = 0; p < 4; ++p) {
                    int ca = c0 + 2 * p, cb = ca + 1;
                    float va = asf(tw[p] << 16)        * s_a[ca] + s_b[ca];
                    float vb = asf(tw[p] & 0xffff0000u) * s_a[cb] + s_b[cb];
                    if (RELU) { va = fmaxf(va, 0.f); vb = fmaxf(vb, 0.f); }
                    r[2 * p]     = asf(hw[p] << 16) + va;
                    r[2 * p + 1] = asf(hw[p] & 0xffff0000u) + vb;
                }
                if (FINAL) {
                    *(float4*)(Out + (size_t)gr * 128 + c0)     = make_float4(r[0], r[1], r[2], r[3]);
                    *(float4*)(Out + (size_t)gr * 128 + c0 + 4) = make_float4(r[4], r[5], r[6], r[7]);
                } else {
                    unsigned o[4];
                    #pragma unroll
                    for (int p = 0; p < 4; ++p)
                        o[p] = (unsigned)f2bf(r[2 * p]) | ((unsigned)f2bf(r[2 * p + 1]) << 16);
                    *(uint4*)(Hbf + (size_t)gr * 128 + c0) = make_uint4(o[0], o[1], o[2], o[3]);
                }
            }
        }
        if (sub == 0) __syncthreads();   // tile reused by subtile 1
    }
}

// ---------------- host
static inline size_t al256(size_t x) { return (x + 255) & ~(size_t)255; }

extern "C" void kernel_launch(void* const* d_in, const int* in_sizes, int n_in,
                              void* d_out, int out_size, void* d_ws, size_t ws_size,
                              hipStream_t stream) {
    const float* x    = (const float*)d_in[0];
    const int*   ei   = (const int*)d_in[1];
    const float* ew   = (const float*)d_in[2];
    const float* W_in = (const float*)d_in[3];
    const float* b_in = (const float*)d_in[4];
    const float* Ws[3] = {(const float*)d_in[5],  (const float*)d_in[11], (const float*)d_in[17]};
    const float* bs[3] = {(const float*)d_in[6],  (const float*)d_in[12], (const float*)d_in[18]};
    const float* Wn[3] = {(const float*)d_in[7],  (const float*)d_in[13], (const float*)d_in[19]};
    const float* bn[3] = {(const float*)d_in[8],  (const float*)d_in[14], (const float*)d_in[20]};
    const float* g[3]  = {(const float*)d_in[9],  (const float*)d_in[15], (const float*)d_in[21]};
    const float* be[3] = {(const float*)d_in[10], (const float*)d_in[16], (const float*)d_in[22]};

    char* ws = (char*)d_ws;
    size_t off = 0;
    const size_t nElem = (size_t)N_NODESC * DIM;          // 12.8M
    unsigned short* hbf    = (unsigned short*)(ws + off); off = al256(off + nElem * 2);
    unsigned short* xnbf   = (unsigned short*)(ws + off); off = al256(off + nElem * 2);
    int2*           tmp    = (int2*)(ws + off);           off = al256(off + (size_t)N_EDGESC * 8);
    unsigned short* wt     = (unsigned short*)(ws + off); off = al256(off + 7 * 16384 * 2);
    int*            offs   = (int*)(ws + off);            off = al256(off + ((size_t)N_NODESC + 1) * 4);
    int2*           edges  = (int2*)(ws + off);           off = al256(off + (size_t)N_EDGESC * 8 + 64);
    int*            G      = (int*)(ws + off);            off = al256(off + (size_t)NBUCK * 256 * 4);
    int*            Base   = (int*)(ws + off);            off = al256(off + (size_t)NBUCK * 256 * 4);
    int*            colbase= (int*)(ws + off);            off = al256(off + (size_t)(NBUCK + 1) * 4);
    float*          stats  = (float*)(ws + off);          off = al256(off + 3 * 256 * 4 + 256);
    int*            ctrs   = (int*)(stats + 3 * 256);     // 3 barrier counters, zeroed with stats

    (void)hipMemsetAsync(stats, 0, 3 * 256 * 4 + 256, stream);

    k_wcvt<<<448, 256, 0, stream>>>(W_in, Ws[0], Wn[0], Ws[1], Wn[1], Ws[2], Wn[2], wt);

    // atomic-free CSR build (two-level counting sort)
    k_chist<<<CSBLK, 256, 0, stream>>>(ei, G);
    k_csum<<<1, 256, 0, stream>>>(G, colbase, offs);
    k_base<<<NBUCK, 256, 0, stream>>>(G, colbase, Base);
    k_part<<<CSBLK, 256, 0, stream>>>(ei, ew, Base, tmp);
    k_fine<<<NBUCK, 256, 0, stream>>>(tmp, colbase, offs, edges);

    k_gemm_in<<<GB, 256, 0, stream>>>(x, wt, b_in, hbf, N_NODESC);

    for (int l = 0; l < 3; ++l) {
        k_agg<<<12500, 256, 0, stream>>>(hbf, offs, edges, xnbf);
        if (l < 2)
            k_gemm_bn<1, 0><<<FB, 256, 0, stream>>>(hbf, xnbf,
                                                    wt + (size_t)(1 + 2 * l) * 16384,
                                                    wt + (size_t)(2 + 2 * l) * 16384,
                                                    bs[l], bn[l], g[l], be[l],
                                                    hbf, nullptr,
                                                    stats + l * 256, stats + l * 256 + 128,
                                                    ctrs + l, N_NODESC);
        else
            k_gemm_bn<0, 1><<<FB, 256, 0, stream>>>(hbf, xnbf,
                                                    wt + (size_t)(1 + 2 * l) * 16384,
                                                    wt + (size_t)(2 + 2 * l) * 16384,
                                                    bs[l], bn[l], g[l], be[l],
                                                    hbf, (float*)d_out,
                                                    stats + l * 256, stats + l * 256 + 128,
                                                    ctrs + l, N_NODESC);
    }
}

// Round 9
// 555.551 us; speedup vs baseline: 1.3371x; 1.2355x over previous
//
#include <hip/hip_runtime.h>

#define N_NODESC 100000
#define N_EDGESC 1600000
#define DIM 128
#define GB 782        // ceil(100000 / 128) gemm blocks
#define HB 6250       // bn blocks
#define TPAD 136      // LDS tile row stride in shorts

// ---- counting-sort CSR build geometry
#define NBUCK 391     // ceil(100000 / 256) coarse buckets (256 nodes each)
#define CSBLK 256     // chunk blocks
#define CHUNK 6250    // edges per chunk block (256 * 6250 = 1.6M exactly)
#define CAPB  6144    // LDS staging capacity per bucket (expect max ~4400)

typedef __bf16 bf16x8 __attribute__((ext_vector_type(8)));
typedef unsigned short u16x8 __attribute__((ext_vector_type(8)));
typedef float f32x4 __attribute__((ext_vector_type(4)));

__device__ __forceinline__ float asf(unsigned u) { return __uint_as_float(u); }
__device__ __forceinline__ unsigned short f2bf(float f) {
    unsigned u = __float_as_uint(f);
    u += 0x7fffu + ((u >> 16) & 1u);
    return (unsigned short)(u >> 16);
}
__device__ __forceinline__ bf16x8 pack8(const float* f) {
    u16x8 u;
    #pragma unroll
    for (int i = 0; i < 8; ++i) u[i] = f2bf(f[i]);
    return __builtin_bit_cast(bf16x8, u);
}

// ---------------- weight convert: 7 matrices fp32 [k][c] -> bf16 FRAGMENT-MAJOR:
// linear index = ((kt*8 + nt)*64 + lane)*8 + j  maps to  W[(kt*32 + quad*8 + j)*128 + nt*16 + l15]
__global__ __launch_bounds__(256) void k_wcvt(const float* __restrict__ w0, const float* __restrict__ w1,
                                              const float* __restrict__ w2, const float* __restrict__ w3,
                                              const float* __restrict__ w4, const float* __restrict__ w5,
                                              const float* __restrict__ w6, unsigned short* __restrict__ wt) {
    int gid = blockIdx.x * 256 + threadIdx.x;   // 0..114687
    int m = gid >> 14;
    int r = gid & 16383;
    int j = r & 7;
    int lane = (r >> 3) & 63;
    int nt = (r >> 9) & 7;
    int kt = (r >> 12) & 3;
    int quad = lane >> 4;
    int l15 = lane & 15;
    const float* src;
    switch (m) {
        case 0: src = w0; break; case 1: src = w1; break; case 2: src = w2; break;
        case 3: src = w3; break; case 4: src = w4; break; case 5: src = w5; break;
        default: src = w6; break;
    }
    wt[gid] = f2bf(src[(kt * 32 + quad * 8 + j) * 128 + nt * 16 + l15]);
}

// ---------------- CSR pass A: per-chunk coarse histogram (LDS atomics only)
__global__ __launch_bounds__(256) void k_chist(const int* __restrict__ ei, int* __restrict__ G) {
    __shared__ int h[NBUCK];
    int tid = threadIdx.x, blk = blockIdx.x;
    for (int b = tid; b < NBUCK; b += 256) h[b] = 0;
    __syncthreads();
    int e0 = blk * CHUNK;
    #pragma unroll 5
    for (int it = 0; it < 25; ++it) {
        int r = it * 256 + tid;
        if (r < CHUNK) {
            int dst = ei[N_EDGESC + e0 + r];
            atomicAdd(&h[dst >> 8], 1);
        }
    }
    __syncthreads();
    for (int b = tid; b < NBUCK; b += 256) G[b * 256 + blk] = h[b];
}

// ---------------- CSR pass B1: bucket totals + exclusive scan -> colbase[392]
__global__ __launch_bounds__(256) void k_csum(const int* __restrict__ G, int* __restrict__ colbase,
                                              int* __restrict__ offs) {
    __shared__ int t[NBUCK + 1];
    int tid = threadIdx.x;
    for (int b = tid; b < NBUCK; b += 256) {
        int s = 0;
        const int* col = G + b * 256;
        #pragma unroll 8
        for (int i = 0; i < 256; ++i) s += col[i];
        t[b] = s;
    }
    __syncthreads();
    if (tid < 64) {
        int lane = tid;
        int loc[7];
        int s = 0;
        #pragma unroll
        for (int j = 0; j < 7; ++j) {
            int idx = lane * 7 + j;
            loc[j] = (idx < NBUCK) ? t[idx] : 0;
            s += loc[j];
        }
        int incl = s;
        #pragma unroll
        for (int d = 1; d < 64; d <<= 1) { int tt = __shfl_up(incl, d, 64); if (lane >= d) incl += tt; }
        int run = incl - s;
        #pragma unroll
        for (int j = 0; j < 7; ++j) {
            int idx = lane * 7 + j;
            if (idx < NBUCK + 1) t[idx] = run;
            run += loc[j];
        }
    }
    __syncthreads();
    for (int b = tid; b < NBUCK + 1; b += 256) colbase[b] = t[b];
    if (tid == 0) offs[N_NODESC] = N_EDGESC;
}

// ---------------- CSR pass B2: per-bucket column scan -> Base[bucket][block]
__global__ __launch_bounds__(256) void k_base(const int* __restrict__ G, const int* __restrict__ colbase,
                                              int* __restrict__ Base) {
    __shared__ int wsum[4];
    int b = blockIdx.x;
    int tid = threadIdx.x;
    int lane = tid & 63, wid = tid >> 6;
    int v = G[b * 256 + tid];
    int incl = v;
    #pragma unroll
    for (int d = 1; d < 64; d <<= 1) { int tt = __shfl_up(incl, d, 64); if (lane >= d) incl += tt; }
    if (lane == 63) wsum[wid] = incl;
    __syncthreads();
    if (tid == 0) { int s = 0; for (int k = 0; k < 4; ++k) { int tt = wsum[k]; wsum[k] = s; s += tt; } }
    __syncthreads();
    Base[b * 256 + tid] = colbase[b] + wsum[wid] + incl - v;
}

// ---------------- CSR pass C: bucket-grouped scatter of packed 8B records (LDS cursors)
__global__ __launch_bounds__(256) void k_part(const int* __restrict__ ei, const float* __restrict__ ew,
                                              const int* __restrict__ Base, int2* __restrict__ tmp) {
    __shared__ int cur[NBUCK];
    int tid = threadIdx.x, blk = blockIdx.x;
    for (int b = tid; b < NBUCK; b += 256) cur[b] = Base[b * 256 + blk];
    __syncthreads();
    int e0 = blk * CHUNK;
    for (int it = 0; it < 25; ++it) {
        int r = it * 256 + tid;
        if (r < CHUNK) {
            int e = e0 + r;
            int src = ei[e];
            int dst = ei[N_EDGESC + e];
            float w = ew[e];
            int pos = atomicAdd(&cur[dst >> 8], 1);
            tmp[pos] = make_int2(src | ((dst & 255) << 17), __float_as_int(w));
        }
    }
}

// ---------------- CSR pass D: per-bucket fine counting sort entirely in LDS
__global__ __launch_bounds__(256) void k_fine(const int2* __restrict__ tmp, const int* __restrict__ colbase,
                                              int* __restrict__ offs, int2* __restrict__ edges) {
    __shared__ int2 recs[CAPB];
    __shared__ int hist[256];
    __shared__ int cur[256];
    __shared__ int wsum[4];
    int tid = threadIdx.x, b = blockIdx.x;
    int start = colbase[b], end = colbase[b + 1];
    int size = end - start;
    bool staged = (size <= CAPB);
    hist[tid] = 0;
    __syncthreads();
    for (int i = tid; i < size; i += 256) {
        int2 r = tmp[start + i];
        if (staged) recs[i] = r;
        atomicAdd(&hist[(r.x >> 17) & 255], 1);
    }
    __syncthreads();
    int lane = tid & 63, wid = tid >> 6;
    int v = hist[tid];
    int incl = v;
    #pragma unroll
    for (int d = 1; d < 64; d <<= 1) { int tt = __shfl_up(incl, d, 64); if (lane >= d) incl += tt; }
    if (lane == 63) wsum[wid] = incl;
    __syncthreads();
    if (tid == 0) { int s = 0; for (int k = 0; k < 4; ++k) { int tt = wsum[k]; wsum[k] = s; s += tt; } }
    __syncthreads();
    int excl = wsum[wid] + incl - v;
    cur[tid] = excl;
    int node = b * 256 + tid;
    if (node < N_NODESC) offs[node] = start + excl;
    __syncthreads();
    for (int i = tid; i < size; i += 256) {
        int2 r = staged ? recs[i] : tmp[start + i];
        int f = (r.x >> 17) & 255;
        int p = atomicAdd(&cur[f], 1);
        edges[start + p] = make_int2(r.x & 0x1FFFF, r.y);
    }
}

// ---------------- aggregation: HALF-WAVE per node (2 nodes/wave) -- round-1 structure (57 us)
__global__ __launch_bounds__(256) void k_agg(const unsigned short* __restrict__ hbf, const int* __restrict__ offs,
                                             const int2* __restrict__ edges, unsigned short* __restrict__ xnbf) {
    int tid = threadIdx.x;
    int q = tid & 15;
    int sub = (tid >> 4) & 1;
    int n = blockIdx.x * 8 + (tid >> 5);
    int s = offs[n], e = offs[n + 1];
    float acc[8] = {};
    float wsum = 0.f;
    for (int j = s; j < e; j += 8) {
        int idx[4];
        bool pr[4];
        int2 rec[4];
        #pragma unroll
        for (int u = 0; u < 4; ++u) {
            idx[u] = j + u * 2 + sub;
            pr[u] = idx[u] < e;
            rec[u] = edges[pr[u] ? idx[u] : s];
        }
        uint4 v[4];
        float w[4];
        #pragma unroll
        for (int u = 0; u < 4; ++u) {
            w[u] = pr[u] ? __int_as_float(rec[u].y) : 0.f;
            v[u] = *(const uint4*)(hbf + (size_t)rec[u].x * 128 + q * 8);
        }
        #pragma unroll
        for (int u = 0; u < 4; ++u) {
            unsigned uu[4] = {v[u].x, v[u].y, v[u].z, v[u].w};
            #pragma unroll
            for (int k = 0; k < 4; ++k) {
                acc[2 * k]     += w[u] * asf(uu[k] << 16);
                acc[2 * k + 1] += w[u] * asf(uu[k] & 0xffff0000u);
            }
            wsum += w[u];
        }
    }
    #pragma unroll
    for (int k = 0; k < 8; ++k) acc[k] += __shfl_xor(acc[k], 16, 64);
    wsum += __shfl_xor(wsum, 16, 64);
    float inv = 1.f / fmaxf(wsum, 1.f);
    if (((tid >> 4) & 1) == 0) {
        unsigned o[4];
        #pragma unroll
        for (int k = 0; k < 4; ++k)
            o[k] = (unsigned)f2bf(acc[2 * k] * inv) | ((unsigned)f2bf(acc[2 * k + 1] * inv) << 16);
        *(uint4*)(xnbf + (size_t)n * 128 + q * 8) = make_uint4(o[0], o[1], o[2], o[3]);
    }
}

// ---------------- input GEMM: hbf = bf16(relu(x @ W_in + b)); W staged in LDS once/block,
// tile aliases the weight LDS after MFMA (round-1 structure, 3 blocks/CU).
__global__ __launch_bounds__(256, 3) void k_gemm_in(const float* __restrict__ X,
                                                    const unsigned short* __restrict__ WF,
                                                    const float* __restrict__ bias,
                                                    unsigned short* __restrict__ Hbf, int M) {
    __shared__ unsigned short smem[128 * TPAD];
    int tid = threadIdx.x;
    int lane = tid & 63;
    int wid = tid >> 6;
    int l15 = lane & 15;
    int quad = lane >> 4;
    #pragma unroll
    for (int it = 0; it < 8; ++it) {
        int idx = (it * 256 + tid) * 8;
        *(uint4*)(smem + idx) = *(const uint4*)(WF + idx);
    }
    int rowbase = blockIdx.x * 128 + wid * 32;
    bf16x8 a[2][4];
    #pragma unroll
    for (int rs = 0; rs < 2; ++rs) {
        int ra = min(rowbase + rs * 16 + l15, M - 1);
        float buf[4][8];
        #pragma unroll
        for (int kt = 0; kt < 4; ++kt) {
            int k0 = kt * 32 + quad * 8;
            *(float4*)(buf[kt])     = *(const float4*)(X + (size_t)ra * 128 + k0);
            *(float4*)(buf[kt] + 4) = *(const float4*)(X + (size_t)ra * 128 + k0 + 4);
        }
        #pragma unroll
        for (int kt = 0; kt < 4; ++kt) a[rs][kt] = pack8(buf[kt]);
    }
    __syncthreads();
    f32x4 acc[2][8] = {};
    #pragma unroll
    for (int kt = 0; kt < 4; ++kt) {
        #pragma unroll
        for (int nt = 0; nt < 8; ++nt) {
            bf16x8 b = *(const bf16x8*)(smem + ((kt * 8 + nt) * 64 + lane) * 8);
            #pragma unroll
            for (int rs = 0; rs < 2; ++rs)
                acc[rs][nt] = __builtin_amdgcn_mfma_f32_16x16x32_bf16(a[rs][kt], b, acc[rs][nt], 0, 0, 0);
        }
    }
    __syncthreads();
    #pragma unroll
    for (int nt = 0; nt < 8; ++nt) {
        int c = nt * 16 + l15;
        float bv = bias[c];
        #pragma unroll
        for (int rs = 0; rs < 2; ++rs) {
            #pragma unroll
            for (int i = 0; i < 4; ++i) {
                int rl = wid * 32 + rs * 16 + quad * 4 + i;
                float v = fmaxf(acc[rs][nt][i] + bv, 0.f);
                smem[rl * TPAD + c] = f2bf(v);
            }
        }
    }
    __syncthreads();
    int rl = tid >> 1;
    int cs = (tid & 1) * 64;
    int gr = blockIdx.x * 128 + rl;
    if (gr < M) {
        #pragma unroll
        for (int k = 0; k < 8; ++k) {
            uint4 v = *(const uint4*)(smem + rl * TPAD + cs + k * 8);
            *(uint4*)(Hbf + (size_t)gr * 128 + cs + k * 8) = v;
        }
    }
}

// ---------------- layer GEMM: t_bf16 = h@Ws + xn@Wn + (bs+bn), + column stats.
// SPLIT STAGING: Ws (32KB) staged, MFMA pass 1; Wn restaged over it, MFMA pass 2.
// LDS = 34.8KB (tile only, weights alias) -> 4 blocks/CU (was 2). Only one fragment
// set (ah or ax) live per pass -> fits the 128-VGPR cap of launch_bounds(256,4).
__global__ __launch_bounds__(256, 4) void k_gemm_layer(const unsigned short* __restrict__ Abf,
                                                       const unsigned short* __restrict__ Xbf,
                                                       const unsigned short* __restrict__ WsF,
                                                       const unsigned short* __restrict__ WnF,
                                                       const float* __restrict__ bs, const float* __restrict__ bn,
                                                       unsigned short* __restrict__ Tb,
                                                       float* __restrict__ colsum, float* __restrict__ colsq,
                                                       int M) {
    __shared__ unsigned short smem[128 * TPAD];   // weights stage in [0..16384); tile aliases
    __shared__ float s_sum[128];
    __shared__ float s_sq[128];
    int tid = threadIdx.x;
    if (tid < 128) { s_sum[tid] = 0.f; s_sq[tid] = 0.f; }
    int lane = tid & 63;
    int wid = tid >> 6;
    int l15 = lane & 15;
    int quad = lane >> 4;
    int rowbase = blockIdx.x * 128 + wid * 32;
    // ---- pass 1: h @ Ws
    bf16x8 af[2][4];
    #pragma unroll
    for (int rs = 0; rs < 2; ++rs) {
        int ra = min(rowbase + rs * 16 + l15, M - 1);
        #pragma unroll
        for (int kt = 0; kt < 4; ++kt)
            af[rs][kt] = *(const bf16x8*)(Abf + (size_t)ra * 128 + kt * 32 + quad * 8);
    }
    #pragma unroll
    for (int it = 0; it < 8; ++it) {
        int idx = (it * 256 + tid) * 8;
        *(uint4*)(smem + idx) = *(const uint4*)(WsF + idx);
    }
    __syncthreads();
    f32x4 acc[2][8] = {};
    #pragma unroll
    for (int kt = 0; kt < 4; ++kt) {
        #pragma unroll
        for (int nt = 0; nt < 8; ++nt) {
            bf16x8 bsv = *(const bf16x8*)(smem + ((kt * 8 + nt) * 64 + lane) * 8);
            #pragma unroll
            for (int rs = 0; rs < 2; ++rs)
                acc[rs][nt] = __builtin_amdgcn_mfma_f32_16x16x32_bf16(af[rs][kt], bsv, acc[rs][nt], 0, 0, 0);
        }
    }
    __syncthreads();   // done reading Ws
    // ---- pass 2: xn @ Wn (fragments reuse af registers)
    #pragma unroll
    for (int rs = 0; rs < 2; ++rs) {
        int ra = min(rowbase + rs * 16 + l15, M - 1);
        #pragma unroll
        for (int kt = 0; kt < 4; ++kt)
            af[rs][kt] = *(const bf16x8*)(Xbf + (size_t)ra * 128 + kt * 32 + quad * 8);
    }
    #pragma unroll
    for (int it = 0; it < 8; ++it) {
        int idx = (it * 256 + tid) * 8;
        *(uint4*)(smem + idx) = *(const uint4*)(WnF + idx);
    }
    __syncthreads();
    #pragma unroll
    for (int kt = 0; kt < 4; ++kt) {
        #pragma unroll
        for (int nt = 0; nt < 8; ++nt) {
            bf16x8 bnv = *(const bf16x8*)(smem + ((kt * 8 + nt) * 64 + lane) * 8);
            #pragma unroll
            for (int rs = 0; rs < 2; ++rs)
                acc[rs][nt] = __builtin_amdgcn_mfma_f32_16x16x32_bf16(af[rs][kt], bnv, acc[rs][nt], 0, 0, 0);
        }
    }
    __syncthreads();   // weights dead; tile aliases them
    #pragma unroll
    for (int nt = 0; nt < 8; ++nt) {
        int c = nt * 16 + l15;
        float bv = bs[c] + bn[c];
        float ps = 0.f, pq = 0.f;
        #pragma unroll
        for (int rs = 0; rs < 2; ++rs) {
            #pragma unroll
            for (int i = 0; i < 4; ++i) {
                int rl = wid * 32 + rs * 16 + quad * 4 + i;   // local row 0..127
                int r = blockIdx.x * 128 + rl;
                float v = acc[rs][nt][i] + bv;
                if (r < M) {
                    unsigned short qv = f2bf(v);
                    smem[rl * TPAD + c] = qv;
                    float vq = asf((unsigned)qv << 16);
                    ps += vq; pq += vq * vq;
                }
            }
        }
        ps += __shfl_xor(ps, 16); pq += __shfl_xor(pq, 16);
        ps += __shfl_xor(ps, 32); pq += __shfl_xor(pq, 32);
        if (quad == 0) { atomicAdd(&s_sum[c], ps); atomicAdd(&s_sq[c], pq); }
    }
    __syncthreads();
    int rl = tid >> 1;
    int cs = (tid & 1) * 64;
    int gr = blockIdx.x * 128 + rl;
    if (gr < M) {
        #pragma unroll
        for (int k = 0; k < 8; ++k) {
            uint4 v = *(const uint4*)(smem + rl * TPAD + cs + k * 8);
            *(uint4*)(Tb + (size_t)gr * 128 + cs + k * 8) = v;
        }
    }
    if (tid < 128) atomicAdd(&colsum[tid], s_sum[tid]);
    else atomicAdd(&colsq[tid - 128], s_sq[tid - 128]);
}

// ---------------- BN apply + residual; residual chain lives in bf16 (Hbf)
template <int RELU, int FINAL>
__global__ __launch_bounds__(256) void k_bn(const unsigned short* __restrict__ Tb,
                                            const float* __restrict__ colsum,
                                            const float* __restrict__ colsq, const float* __restrict__ gma,
                                            const float* __restrict__ bta,
                                            unsigned short* __restrict__ Hbf, float* __restrict__ Out) {
    size_t base = ((size_t)blockIdx.x * 256 + threadIdx.x) * 8;
    int c0 = (int)(base & 127);
    uint4 tv = *(const uint4*)(Tb + base);
    unsigned w[4] = {tv.x, tv.y, tv.z, tv.w};
    float tt[8];
    #pragma unroll
    for (int k = 0; k < 4; ++k) {
        tt[2 * k]     = asf(w[k] << 16);
        tt[2 * k + 1] = asf(w[k] & 0xffff0000u);
    }
    uint4 hv = *(const uint4*)(Hbf + base);
    unsigned hw[4] = {hv.x, hv.y, hv.z, hv.w};
    float hh[8];
    #pragma unroll
    for (int k = 0; k < 4; ++k) {
        hh[2 * k]     = asf(hw[k] << 16);
        hh[2 * k + 1] = asf(hw[k] & 0xffff0000u);
    }
    float ss[8], qq[8], gg[8], bb[8];
    *(float4*)ss       = *(const float4*)(colsum + c0);
    *(float4*)(ss + 4) = *(const float4*)(colsum + c0 + 4);
    *(float4*)qq       = *(const float4*)(colsq + c0);
    *(float4*)(qq + 4) = *(const float4*)(colsq + c0 + 4);
    *(float4*)gg       = *(const float4*)(gma + c0);
    *(float4*)(gg + 4) = *(const float4*)(gma + c0 + 4);
    *(float4*)bb       = *(const float4*)(bta + c0);
    *(float4*)(bb + 4) = *(const float4*)(bta + c0 + 4);
    const float invM = 1.0f / (float)N_NODESC;
    float r[8];
    #pragma unroll
    for (int j = 0; j < 8; ++j) {
        float mu = ss[j] * invM;
        float var = qq[j] * invM - mu * mu;
        float is = rsqrtf(var + 1e-5f);
        float v = (tt[j] - mu) * is * gg[j] + bb[j];
        if (RELU) v = fmaxf(v, 0.f);
        r[j] = hh[j] + v;
    }
    if (FINAL) {
        *(float4*)(Out + base)     = make_float4(r[0], r[1], r[2], r[3]);
        *(float4*)(Out + base + 4) = make_float4(r[4], r[5], r[6], r[7]);
    } else {
        unsigned o[4];
        #pragma unroll
        for (int k = 0; k < 4; ++k)
            o[k] = (unsigned)f2bf(r[2 * k]) | ((unsigned)f2bf(r[2 * k + 1]) << 16);
        *(uint4*)(Hbf + base) = make_uint4(o[0], o[1], o[2], o[3]);
    }
}

// ---------------- host
static inline size_t al256(size_t x) { return (x + 255) & ~(size_t)255; }

extern "C" void kernel_launch(void* const* d_in, const int* in_sizes, int n_in,
                              void* d_out, int out_size, void* d_ws, size_t ws_size,
                              hipStream_t stream) {
    const float* x    = (const float*)d_in[0];
    const int*   ei   = (const int*)d_in[1];
    const float* ew   = (const float*)d_in[2];
    const float* W_in = (const float*)d_in[3];
    const float* b_in = (const float*)d_in[4];
    const float* Ws[3] = {(const float*)d_in[5],  (const float*)d_in[11], (const float*)d_in[17]};
    const float* bs[3] = {(const float*)d_in[6],  (const float*)d_in[12], (const float*)d_in[18]};
    const float* Wn[3] = {(const float*)d_in[7],  (const float*)d_in[13], (const float*)d_in[19]};
    const float* bn[3] = {(const float*)d_in[8],  (const float*)d_in[14], (const float*)d_in[20]};
    const float* g[3]  = {(const float*)d_in[9],  (const float*)d_in[15], (const float*)d_in[21]};
    const float* be[3] = {(const float*)d_in[10], (const float*)d_in[16], (const float*)d_in[22]};

    char* ws = (char*)d_ws;
    size_t off = 0;
    const size_t nElem = (size_t)N_NODESC * DIM;          // 12.8M
    unsigned short* hbf    = (unsigned short*)(ws + off); off = al256(off + nElem * 2);
    unsigned short* xnbf   = (unsigned short*)(ws + off); off = al256(off + nElem * 2);
    unsigned short* tbuf   = (unsigned short*)(ws + off); off = al256(off + nElem * 2);
    unsigned short* wt     = (unsigned short*)(ws + off); off = al256(off + 7 * 16384 * 2);
    int*            offs   = (int*)(ws + off);            off = al256(off + ((size_t)N_NODESC + 1) * 4);
    int2*           edges  = (int2*)(ws + off);           off = al256(off + (size_t)N_EDGESC * 8 + 64);
    int*            G      = (int*)(ws + off);            off = al256(off + (size_t)NBUCK * 256 * 4);
    int*            Base   = (int*)(ws + off);            off = al256(off + (size_t)NBUCK * 256 * 4);
    int*            colbase= (int*)(ws + off);            off = al256(off + (size_t)(NBUCK + 1) * 4);
    float*          stats  = (float*)(ws + off);          off = al256(off + 3 * 256 * 4);
    int2*           tmp    = (int2*)tbuf;   // alias: tbuf is dead until layer-0 GEMM

    (void)hipMemsetAsync(stats, 0, 3 * 256 * 4, stream);

    k_wcvt<<<448, 256, 0, stream>>>(W_in, Ws[0], Wn[0], Ws[1], Wn[1], Ws[2], Wn[2], wt);

    // atomic-free CSR build (two-level counting sort)
    k_chist<<<CSBLK, 256, 0, stream>>>(ei, G);
    k_csum<<<1, 256, 0, stream>>>(G, colbase, offs);
    k_base<<<NBUCK, 256, 0, stream>>>(G, colbase, Base);
    k_part<<<CSBLK, 256, 0, stream>>>(ei, ew, Base, tmp);
    k_fine<<<NBUCK, 256, 0, stream>>>(tmp, colbase, offs, edges);

    k_gemm_in<<<GB, 256, 0, stream>>>(x, wt, b_in, hbf, N_NODESC);

    for (int l = 0; l < 3; ++l) {
        k_agg<<<12500, 256, 0, stream>>>(hbf, offs, edges, xnbf);
        k_gemm_layer<<<GB, 256, 0, stream>>>(hbf, xnbf,
                                             wt + (size_t)(1 + 2 * l) * 16384,
                                             wt + (size_t)(2 + 2 * l) * 16384,
                                             bs[l], bn[l], tbuf,
                                             stats + l * 256, stats + l * 256 + 128, N_NODESC);
        if (l < 2)
            k_bn<1, 0><<<HB, 256, 0, stream>>>(tbuf, stats + l * 256, stats + l * 256 + 128,
                                               g[l], be[l], hbf, nullptr);
        else
            k_bn<0, 1><<<HB, 256, 0, stream>>>(tbuf, stats + l * 256, stats + l * 256 + 128,
                                               g[l], be[l], hbf, (float*)d_out);
    }
}